// Round 9
// baseline (702.197 us; speedup 1.0000x reference)
//
#include <hip/hip_runtime.h>
#include <math.h>

// Problem constants
#define Bq 16
#define Cc 256
#define HW 4096      // H*W
#define Mm 512
#define Nn 65536     // B*H*W
#define Oo 256

typedef short bf16x8 __attribute__((ext_vector_type(8)));
typedef float f32x4 __attribute__((ext_vector_type(4)));
typedef unsigned short ushort_t;

// Workspace float offsets (total 50,660,352 floats = 202.6 MB; ws measured ~1.3 GB via poison fill)
#define WS_ROWSUM  0
#define WS_COLSUM  65536
#define WS_BNSUM   66048
#define WS_BNSUMSQ 66304
#define WS_EXS     66560
#define WS_QHI     33620992
#define WS_QLO     42009600
#define WS_MEMT    50398208
#define WS_AHI     50463744
#define WS_ALO     50562048
#define WS_TOTAL   50660352

__device__ __forceinline__ unsigned int bf16rne(float f) {
  unsigned int u = __float_as_uint(f);
  return (u + 0x7FFFu + ((u >> 16) & 1u)) >> 16;   // RNE bf16 bits
}
__device__ __forceinline__ float bf16f(unsigned int h) { return __uint_as_float(h << 16); }
__device__ __forceinline__ void split2(float v0, float v1,
                                       unsigned int& hi, unsigned int& lo) {
  unsigned int h0 = bf16rne(v0), h1 = bf16rne(v1);
  hi = h0 | (h1 << 16);
  unsigned int l0 = bf16rne(v0 - bf16f(h0)), l1 = bf16rne(v1 - bf16f(h1));
  lo = l0 | (l1 << 16);
}

// ---------------------------------------------------------------- k_qt:
//  blocks [0,2048):    transpose query, fp32 norm, emit qnorm hi/lo bf16 [N][C]
//  blocks [2048,2056): cvt mem -> memT bf16 [M][C]
__global__ __launch_bounds__(256) void k_qt(const float* __restrict__ query,
                                            ushort_t* __restrict__ qhiT,
                                            ushort_t* __restrict__ qloT,
                                            const float* __restrict__ mem,
                                            ushort_t* __restrict__ memT) {
  __shared__ float T[256][36];
  __shared__ float S2[8][32];
  __shared__ float invn_s[32];
  int tid = threadIdx.x, bid = blockIdx.x;
  if (bid < 2048) {
    int n0 = bid * 32;
    int b = n0 >> 12, hw0 = n0 & 4095;
    const float* qb = query + (size_t)b * Cc * HW + hw0;
#pragma unroll
    for (int p = 0; p < 8; ++p) {
      int idx = p * 256 + tid;
      int c = idx >> 3, f4 = idx & 7;
      float4 v = *(const float4*)(qb + (size_t)c * HW + f4 * 4);
      *(float4*)&T[c][f4 * 4] = v;
    }
    __syncthreads();
    {
      int n = tid & 31, cq = tid >> 5;
      float s = 0.f;
#pragma unroll
      for (int c = 0; c < 32; ++c) { float v = T[cq * 32 + c][n]; s += v * v; }
      S2[cq][n] = s;
    }
    __syncthreads();
    if (tid < 32) {
      float s = 0.f;
#pragma unroll
      for (int q = 0; q < 8; ++q) s += S2[q][tid];
      invn_s[tid] = 1.f / fmaxf(sqrtf(s), 1e-12f);
    }
    __syncthreads();
#pragma unroll
    for (int p = 0; p < 4; ++p) {
      int idx = p * 256 + tid;
      int n = idx & 31, g = idx >> 5;
      float ivn = invn_s[n];
      unsigned int hv[4], lv[4];
#pragma unroll
      for (int h = 0; h < 4; ++h) {
        int c0 = g * 8 + h * 2;
        split2(T[c0][n] * ivn, T[c0 + 1][n] * ivn, hv[h], lv[h]);
      }
      *(uint4*)(qhiT + (size_t)(n0 + n) * 256 + g * 8) = make_uint4(hv[0], hv[1], hv[2], hv[3]);
      *(uint4*)(qloT + (size_t)(n0 + n) * 256 + g * 8) = make_uint4(lv[0], lv[1], lv[2], lv[3]);
    }
  } else {
    int r0 = (bid - 2048) * 64;
#pragma unroll
    for (int p = 0; p < 8; ++p) {
      int idx = p * 256 + tid;
      int row = idx >> 5, g = idx & 31;
      const float* src = mem + (size_t)(r0 + row) * 256 + g * 8;
      float4 a = *(const float4*)(src);
      float4 c = *(const float4*)(src + 4);
      unsigned int w0 = bf16rne(a.x) | (bf16rne(a.y) << 16);
      unsigned int w1 = bf16rne(a.z) | (bf16rne(a.w) << 16);
      unsigned int w2 = bf16rne(c.x) | (bf16rne(c.y) << 16);
      unsigned int w3 = bf16rne(c.z) | (bf16rne(c.w) << 16);
      *(uint4*)(memT + (size_t)(r0 + row) * 256 + g * 8) = make_uint4(w0, w1, w2, w3);
    }
  }
}

// ---------------------------------------------------------------- k_wm: W' = [Wq | Wc@mem^T] split hi/lo [256][768]
__global__ __launch_bounds__(256) void k_wm(const float* __restrict__ conv_w,
                                            const float* __restrict__ mem,
                                            ushort_t* __restrict__ Ahi,
                                            ushort_t* __restrict__ Alo) {
  __shared__ __align__(16) float Asm[16 * 132];
  __shared__ __align__(16) float Bsm[16 * 132];
  int tid = threadIdx.x, bid = blockIdx.x;
  if (bid >= 8) {
    int b8 = bid - 8;
#pragma unroll
    for (int p = 0; p < 8; ++p) {
      int idx = b8 * 2048 + p * 256 + tid;
      int o = idx >> 6, c4 = (idx & 63) * 4;
      float4 v = *(const float4*)(conv_w + (size_t)o * 512 + c4);
      unsigned int h0, l0, h1, l1;
      split2(v.x, v.y, h0, l0);
      split2(v.z, v.w, h1, l1);
      *(uint2*)(Ahi + (size_t)o * 768 + c4) = make_uint2(h0, h1);
      *(uint2*)(Alo + (size_t)o * 768 + c4) = make_uint2(l0, l1);
    }
    return;
  }
  int tile_o = bid & 1, tile_m = bid >> 1;
  int o0 = tile_o * 128, m0 = tile_m * 128;
  int tx = tid & 15, ty = tid >> 4;
  int akk = tid & 15, ao0 = tid >> 4;
  int bk = tid & 15, bm = tid >> 4;

  float acc[2][2][4][4];
#pragma unroll
  for (int a = 0; a < 2; ++a)
#pragma unroll
    for (int c = 0; c < 2; ++c)
#pragma unroll
      for (int i = 0; i < 4; ++i)
#pragma unroll
        for (int j = 0; j < 4; ++j) acc[a][c][i][j] = 0.f;

  for (int k0 = 0; k0 < Cc; k0 += 16) {
#pragma unroll
    for (int i = 0; i < 8; ++i) {
      int o = ao0 + i * 16;
      Asm[akk * 132 + o] = conv_w[(size_t)(o0 + o) * 512 + 256 + k0 + akk];
    }
#pragma unroll
    for (int i = 0; i < 8; ++i) {
      int m = bm + i * 16;
      Bsm[bk * 132 + m] = mem[(size_t)(m0 + m) * Cc + k0 + bk];
    }
    __syncthreads();
#pragma unroll
    for (int kk = 0; kk < 16; ++kk) {
      float4 a0 = *(const float4*)&Asm[kk * 132 + ty * 4];
      float4 a1 = *(const float4*)&Asm[kk * 132 + 64 + ty * 4];
      float4 b0 = *(const float4*)&Bsm[kk * 132 + tx * 4];
      float4 b1 = *(const float4*)&Bsm[kk * 132 + 64 + tx * 4];
      float av[2][4] = {{a0.x, a0.y, a0.z, a0.w}, {a1.x, a1.y, a1.z, a1.w}};
      float bv[2][4] = {{b0.x, b0.y, b0.z, b0.w}, {b1.x, b1.y, b1.z, b1.w}};
#pragma unroll
      for (int ib = 0; ib < 2; ++ib)
#pragma unroll
        for (int i = 0; i < 4; ++i)
#pragma unroll
          for (int jb = 0; jb < 2; ++jb)
#pragma unroll
            for (int j = 0; j < 4; ++j) acc[ib][jb][i][j] += av[ib][i] * bv[jb][j];
    }
    __syncthreads();
  }
#pragma unroll
  for (int ib = 0; ib < 2; ++ib)
#pragma unroll
    for (int i = 0; i < 4; ++i) {
      int o = o0 + ib * 64 + ty * 4 + i;
#pragma unroll
      for (int jb = 0; jb < 2; ++jb) {
        int mc = m0 + jb * 64 + tx * 4;
        unsigned int h0, l0, h1, l1;
        split2(acc[ib][jb][i][0], acc[ib][jb][i][1], h0, l0);
        split2(acc[ib][jb][i][2], acc[ib][jb][i][3], h1, l1);
        *(uint2*)(Ahi + (size_t)o * 768 + 256 + mc) = make_uint2(h0, h1);
        *(uint2*)(Alo + (size_t)o * 768 + 256 + mc) = make_uint2(l0, l1);
      }
    }
}

// ---------------------------------------------------------------- G1 (MFMA bf16, global-direct operands, no main-loop LDS)
__global__ __launch_bounds__(256) void k_score(const ushort_t* __restrict__ qhiT,
                                               const ushort_t* __restrict__ memT,
                                               float* __restrict__ exs,
                                               float* __restrict__ rowsum,
                                               float* __restrict__ colsum) {
  __shared__ float red[128 * 32];   // epilogue reductions only
  int tid = threadIdx.x, bid = blockIdx.x;
  int m0 = (bid & 3) * 128;
  int n0 = (bid >> 2) * 128;
  int lane = tid & 63;
  int w = tid >> 6, wrow = w >> 1, wcol = w & 1;
  int rlane = lane & 15, klane = (lane >> 4) * 8;

  f32x4 acc[4][4];
#pragma unroll
  for (int i = 0; i < 4; ++i)
#pragma unroll
    for (int j = 0; j < 4; ++j)
#pragma unroll
      for (int e = 0; e < 4; ++e) acc[i][j][e] = 0.f;

  const ushort_t* qbase = qhiT + (size_t)(n0 + wrow * 64 + rlane) * 256 + klane;
  const ushort_t* mbase = memT + (size_t)(m0 + wcol * 64 + rlane) * 256 + klane;

  for (int kt = 0; kt < 4; ++kt) {
#pragma unroll
    for (int ks = 0; ks < 2; ++ks) {
      int k0 = kt * 64 + ks * 32;
      bf16x8 a[4], b[4];
#pragma unroll
      for (int i = 0; i < 4; ++i)
        a[i] = *(const bf16x8*)(qbase + (size_t)(i * 16) * 256 + k0);
#pragma unroll
      for (int j = 0; j < 4; ++j)
        b[j] = *(const bf16x8*)(mbase + (size_t)(j * 16) * 256 + k0);
#pragma unroll
      for (int i = 0; i < 4; ++i)
#pragma unroll
        for (int j = 0; j < 4; ++j)
          acc[i][j] = __builtin_amdgcn_mfma_f32_16x16x32_bf16(a[i], b[j], acc[i][j], 0, 0, 0);
    }
  }

  // epilogue: C/D map col=lane&15, row=(lane>>4)*4+reg  [m89-verified, r8-passed]
  float rp[4][4], cp[4];
#pragma unroll
  for (int i = 0; i < 4; ++i)
#pragma unroll
    for (int r = 0; r < 4; ++r) rp[i][r] = 0.f;
#pragma unroll
  for (int j = 0; j < 4; ++j) cp[j] = 0.f;

#pragma unroll
  for (int i = 0; i < 4; ++i) {
#pragma unroll
    for (int r = 0; r < 4; ++r) {
      int pl = wrow * 64 + i * 16 + (lane >> 4) * 4 + r;
      float* orow = exs + (size_t)(n0 + pl) * Mm + m0;
#pragma unroll
      for (int j = 0; j < 4; ++j) {
        int sl = wcol * 64 + j * 16 + (lane & 15);
        float e = __expf(acc[i][j][r]);      // |score|<=1: no max-shift
        orow[sl] = e;
        rp[i][r] += e;
        cp[j] += e;
      }
    }
  }

#pragma unroll
  for (int i = 0; i < 4; ++i)
#pragma unroll
    for (int r = 0; r < 4; ++r) {
      int pl = wrow * 64 + i * 16 + (lane >> 4) * 4 + r;
      red[pl * 32 + wcol * 16 + (lane & 15)] = rp[i][r];
    }
  __syncthreads();
  if (tid < 128) {
    float s = 0.f;
#pragma unroll
    for (int x = 0; x < 32; ++x) s += red[tid * 32 + x];
    atomicAdd(&rowsum[n0 + tid], s);
  }
  __syncthreads();
#pragma unroll
  for (int j = 0; j < 4; ++j) {
    int sl = wcol * 64 + j * 16 + (lane & 15);
    red[sl * 8 + wrow * 4 + (lane >> 4)] = cp[j];
  }
  __syncthreads();
  if (tid < 128) {
    float s = 0.f;
#pragma unroll
    for (int x = 0; x < 8; ++x) s += red[tid * 8 + x];
    atomicAdd(&colsum[m0 + tid], s);
  }
}

// ---------------------------------------------------------------- fused conv (split-bf16 MFMA) + smm/smq production
// y = W' @ X^T (K=768); X = qnorm (k<256, global hi/lo) | P=e*invrow (k>=256, split in staging).
// tile_o==0 blocks also emit smm = e*invrow and smq = e*invcol during staging.
__global__ __launch_bounds__(256) void k_conv(const ushort_t* __restrict__ Ahi,
                                              const ushort_t* __restrict__ Alo,
                                              const ushort_t* __restrict__ qhiT,
                                              const ushort_t* __restrict__ qloT,
                                              const float* __restrict__ exs,
                                              const float* __restrict__ rowsum,
                                              const float* __restrict__ colsum,
                                              float* __restrict__ y,
                                              float* __restrict__ smm,
                                              float* __restrict__ smq,
                                              float* __restrict__ bnsum,
                                              float* __restrict__ bnsumsq) {
  __shared__ ushort_t BsH[128 * 64], BsL[128 * 64];
  __shared__ float irow[128];
  __shared__ float invc[512];
  int tid = threadIdx.x, bid = blockIdx.x;
  int tile_o = bid & 1, tile_n = bid >> 1;
  int o0 = tile_o * 128, n0 = tile_n * 128;
  int b = n0 >> 12, hw0 = n0 & 4095;
  if (tid < 128) irow[tid] = 1.0f / rowsum[n0 + tid];
  invc[tid] = 1.0f / colsum[tid];
  invc[tid + 256] = 1.0f / colsum[tid + 256];
  int lane = tid & 63;
  int w = tid >> 6, wrow = w >> 1, wcol = w & 1;
  int rlane = lane & 15, klane = (lane >> 4) * 8;

  f32x4 acc[4][4];
#pragma unroll
  for (int i = 0; i < 4; ++i)
#pragma unroll
    for (int j = 0; j < 4; ++j)
#pragma unroll
      for (int e = 0; e < 4; ++e) acc[i][j][e] = 0.f;

  const ushort_t* ahB = Ahi + (size_t)(o0 + wrow * 64 + rlane) * 768 + klane;
  const ushort_t* alB = Alo + (size_t)(o0 + wrow * 64 + rlane) * 768 + klane;
  const ushort_t* qhB = qhiT + (size_t)(n0 + wcol * 64 + rlane) * 256 + klane;
  const ushort_t* qlB = qloT + (size_t)(n0 + wcol * 64 + rlane) * 256 + klane;
  uint2* BsH2 = (uint2*)BsH;
  uint2* BsL2 = (uint2*)BsL;
  __syncthreads();   // irow/invc visible

  // ---- kt 0..3 (qnorm half): fully global-direct, no barriers
  for (int kt = 0; kt < 4; ++kt) {
#pragma unroll
    for (int ks = 0; ks < 2; ++ks) {
      int k0 = kt * 64 + ks * 32;
      bf16x8 ah[4], al[4], bh[4], bl[4];
#pragma unroll
      for (int i = 0; i < 4; ++i) {
        ah[i] = *(const bf16x8*)(ahB + (size_t)(i * 16) * 768 + k0);
        al[i] = *(const bf16x8*)(alB + (size_t)(i * 16) * 768 + k0);
      }
#pragma unroll
      for (int j = 0; j < 4; ++j) {
        bh[j] = *(const bf16x8*)(qhB + (size_t)(j * 16) * 256 + k0);
        bl[j] = *(const bf16x8*)(qlB + (size_t)(j * 16) * 256 + k0);
      }
#pragma unroll
      for (int i = 0; i < 4; ++i)
#pragma unroll
        for (int j = 0; j < 4; ++j) {
          acc[i][j] = __builtin_amdgcn_mfma_f32_16x16x32_bf16(al[i], bh[j], acc[i][j], 0, 0, 0);
          acc[i][j] = __builtin_amdgcn_mfma_f32_16x16x32_bf16(ah[i], bl[j], acc[i][j], 0, 0, 0);
          acc[i][j] = __builtin_amdgcn_mfma_f32_16x16x32_bf16(ah[i], bh[j], acc[i][j], 0, 0, 0);
        }
    }
  }

  // ---- kt 4..11 (P half): stage split-P in LDS, A global-direct
  for (int kt2 = 0; kt2 < 8; ++kt2) {
    int kg = 256 + kt2 * 64;      // k in W' space
    int kc = kt2 * 64;            // column in exs/smm/smq space
#pragma unroll
    for (int p = 0; p < 8; ++p) {
      int idx = p * 256 + tid;
      int row = idx >> 4, f4 = idx & 15;
      int col = kc + f4 * 4;
      float ir = irow[row];
      float4 v = *(const float4*)(exs + (size_t)(n0 + row) * Mm + col);
      float4 pv = make_float4(v.x * ir, v.y * ir, v.z * ir, v.w * ir);
      if (tile_o == 0) {
        *(float4*)(smm + (size_t)(n0 + row) * Mm + col) = pv;
        float4 ic = *(const float4*)&invc[col];
        *(float4*)(smq + (size_t)(n0 + row) * Mm + col) =
            make_float4(v.x * ic.x, v.y * ic.y, v.z * ic.z, v.w * ic.w);
      }
      unsigned int h0, l0, h1, l1;
      split2(pv.x, pv.y, h0, l0);
      split2(pv.z, pv.w, h1, l1);
      int g = f4 >> 1, half = f4 & 1;
      int G = g ^ (row & 7);
      BsH2[(row * 8 + G) * 2 + half] = make_uint2(h0, h1);
      BsL2[(row * 8 + G) * 2 + half] = make_uint2(l0, l1);
    }
    __syncthreads();
#pragma unroll
    for (int ks = 0; ks < 2; ++ks) {
      int k0 = kg + ks * 32;
      bf16x8 ah[4], al[4], bh[4], bl[4];
#pragma unroll
      for (int i = 0; i < 4; ++i) {
        ah[i] = *(const bf16x8*)(ahB + (size_t)(i * 16) * 768 + k0);
        al[i] = *(const bf16x8*)(alB + (size_t)(i * 16) * 768 + k0);
      }
#pragma unroll
      for (int j = 0; j < 4; ++j) {
        int row = wcol * 64 + j * 16 + (lane & 15);
        int G = ((lane >> 4) + ks * 4) ^ (row & 7);
        bh[j] = ((const bf16x8*)BsH)[row * 8 + G];
        bl[j] = ((const bf16x8*)BsL)[row * 8 + G];
      }
#pragma unroll
      for (int i = 0; i < 4; ++i)
#pragma unroll
        for (int j = 0; j < 4; ++j) {
          acc[i][j] = __builtin_amdgcn_mfma_f32_16x16x32_bf16(al[i], bh[j], acc[i][j], 0, 0, 0);
          acc[i][j] = __builtin_amdgcn_mfma_f32_16x16x32_bf16(ah[i], bl[j], acc[i][j], 0, 0, 0);
          acc[i][j] = __builtin_amdgcn_mfma_f32_16x16x32_bf16(ah[i], bh[j], acc[i][j], 0, 0, 0);
        }
    }
    __syncthreads();
  }

  // ---- epilogue: y store + BN partial sums
  float rp[4][4], rq[4][4];
#pragma unroll
  for (int i = 0; i < 4; ++i)
#pragma unroll
    for (int r = 0; r < 4; ++r) { rp[i][r] = 0.f; rq[i][r] = 0.f; }

#pragma unroll
  for (int i = 0; i < 4; ++i) {
#pragma unroll
    for (int r = 0; r < 4; ++r) {
      int pl = wrow * 64 + i * 16 + (lane >> 4) * 4 + r;
      float* orow = y + (size_t)b * Oo * HW + (size_t)(o0 + pl) * HW + hw0;
#pragma unroll
      for (int j = 0; j < 4; ++j) {
        int sl = wcol * 64 + j * 16 + (lane & 15);
        float v = acc[i][j][r];
        orow[sl] = v;
        rp[i][r] += v;
        rq[i][r] += v * v;
      }
    }
  }

  float* red = (float*)BsH;
#pragma unroll
  for (int i = 0; i < 4; ++i)
#pragma unroll
    for (int r = 0; r < 4; ++r) {
      int pl = wrow * 64 + i * 16 + (lane >> 4) * 4 + r;
      red[pl * 32 + wcol * 16 + (lane & 15)] = rp[i][r];
    }
  __syncthreads();
  if (tid < 128) {
    float s = 0.f;
#pragma unroll
    for (int x = 0; x < 32; ++x) s += red[tid * 32 + x];
    atomicAdd(&bnsum[o0 + tid], s);
  }
  __syncthreads();
#pragma unroll
  for (int i = 0; i < 4; ++i)
#pragma unroll
    for (int r = 0; r < 4; ++r) {
      int pl = wrow * 64 + i * 16 + (lane >> 4) * 4 + r;
      red[pl * 32 + wcol * 16 + (lane & 15)] = rq[i][r];
    }
  __syncthreads();
  if (tid < 128) {
    float s = 0.f;
#pragma unroll
    for (int x = 0; x < 32; ++x) s += red[tid * 32 + x];
    atomicAdd(&bnsumsq[o0 + tid], s);
  }
}

// ---------------------------------------------------------------- y = relu(BN(y)) in-place
__global__ __launch_bounds__(256) void k_final_y(float4* __restrict__ y4,
                                                 const float* __restrict__ bnsum,
                                                 const float* __restrict__ bnsumsq,
                                                 const float* __restrict__ gamma,
                                                 const float* __restrict__ beta) {
  int g = blockIdx.x * 256 + threadIdx.x;
  int o = (g >> 10) & 255;
  float mean = bnsum[o] * (1.f / Nn);
  float var = bnsumsq[o] * (1.f / Nn) - mean * mean;
  float s = gamma[o] * rsqrtf(var + 1e-5f);
  float t = beta[o] - mean * s;
  float4 v = y4[g];
  v.x = fmaxf(v.x * s + t, 0.f);
  v.y = fmaxf(v.y * s + t, 0.f);
  v.z = fmaxf(v.z * s + t, 0.f);
  v.w = fmaxf(v.w * s + t, 0.f);
  y4[g] = v;
}

// ---------------------------------------------------------------- launch
extern "C" void kernel_launch(void* const* d_in, const int* in_sizes, int n_in,
                              void* d_out, int out_size, void* d_ws, size_t ws_size,
                              hipStream_t stream) {
  (void)in_sizes; (void)n_in; (void)out_size;
  if (ws_size < (size_t)WS_TOTAL * sizeof(float)) return;  // loud failure, no corruption
  const float* query  = (const float*)d_in[0];
  const float* mem    = (const float*)d_in[1];
  const float* conv_w = (const float*)d_in[2];
  const float* gamma  = (const float*)d_in[3];
  const float* beta   = (const float*)d_in[4];
  float* out = (float*)d_out;
  float* y   = out;                    // 16,777,216 floats
  float* smq = out + 16777216;         // 33,554,432 floats
  float* smm = smq + 33554432;         // 33,554,432 floats
  float* ws = (float*)d_ws;
  float* rowsum  = ws + WS_ROWSUM;
  float* colsum  = ws + WS_COLSUM;
  float* bnsum   = ws + WS_BNSUM;
  float* bnsumsq = ws + WS_BNSUMSQ;
  float* exs     = ws + WS_EXS;
  ushort_t* qhiT = (ushort_t*)(ws + WS_QHI);
  ushort_t* qloT = (ushort_t*)(ws + WS_QLO);
  ushort_t* memT = (ushort_t*)(ws + WS_MEMT);
  ushort_t* Ahi  = (ushort_t*)(ws + WS_AHI);
  ushort_t* Alo  = (ushort_t*)(ws + WS_ALO);

  hipMemsetAsync(ws, 0, 66560 * sizeof(float), stream);

  k_qt<<<2056, 256, 0, stream>>>(query, qhiT, qloT, mem, memT);
  k_wm<<<16, 256, 0, stream>>>(conv_w, mem, Ahi, Alo);
  k_score<<<2048, 256, 0, stream>>>(qhiT, memT, exs, rowsum, colsum);
  k_conv<<<1024, 256, 0, stream>>>(Ahi, Alo, qhiT, qloT, exs, rowsum, colsum,
                                   y, smm, smq, bnsum, bnsumsq);
  k_final_y<<<16384, 256, 0, stream>>>((float4*)y, bnsum, bnsumsq, gamma, beta);
}